// Round 3
// baseline (1054.899 us; speedup 1.0000x reference)
//
#include <hip/hip_runtime.h>
#include <cstdint>
#include <cstddef>

// MLSWA transformer block, B=2 N=2048 D=1024 H=16 HD=64 DFF=4096.
// NOTE: the multi-level window mask is ALL-TRUE for N=2048 (level-2 positions
// span 0..7, window 16) -> plain full attention.

using u16 = unsigned short;
using u32 = unsigned int;

typedef __attribute__((ext_vector_type(8)))  short bf16x8;
typedef __attribute__((ext_vector_type(4)))  float f32x4;
typedef __attribute__((ext_vector_type(16))) float f32x16;

#define DEV __device__ __forceinline__

DEV u16 f2bf(float f) {
  u32 u = __builtin_bit_cast(u32, f);
  u32 r = (u + 0x7FFFu + ((u >> 16) & 1u)) >> 16;
  return (u16)r;
}
DEV float bf2f(u16 u) { return __builtin_bit_cast(float, (u32)u << 16); }
DEV u32 pk2(float a, float b) { return (u32)f2bf(a) | ((u32)f2bf(b) << 16); }
DEV u32 cvtpk(float lo, float hi) {
  u32 r;
  asm("v_cvt_pk_bf16_f32 %0, %1, %2" : "=v"(r) : "v"(lo), "v"(hi));
  return r;
}
DEV float fexp2(float x) { return __builtin_amdgcn_exp2f(x); }

DEV void gload_lds16(const void* g, void* lds) {
  __builtin_amdgcn_global_load_lds(
      (const __attribute__((address_space(1))) u32*)g,
      (__attribute__((address_space(3))) u32*)lds, 16, 0, 0);
}

// ---------------- weight transpose + bf16 convert: in (R x C) f32 -> out (C x R) bf16
__global__ __launch_bounds__(256) void k_transpose_bf16(const float* __restrict__ in,
                                                        u16* __restrict__ out, int R, int C) {
  __shared__ float ts[32][33];
  int n0 = blockIdx.x * 32, r0 = blockIdx.y * 32;
  int t = threadIdx.x;
  int c = t & 31, r = t >> 5; // r in 0..7
#pragma unroll
  for (int j = 0; j < 4; ++j)
    ts[r + 8 * j][c] = in[(size_t)(r0 + r + 8 * j) * C + n0 + c];
  __syncthreads();
#pragma unroll
  for (int j = 0; j < 4; ++j)
    out[(size_t)(n0 + r + 8 * j) * R + r0 + c] = f2bf(ts[c][r + 8 * j]);
}

// ---------------- layernorm: one block per row (D=1024), bf16 out
__global__ __launch_bounds__(256) void k_layernorm(const float* __restrict__ x,
                                                   const float* __restrict__ g,
                                                   const float* __restrict__ be,
                                                   u16* __restrict__ o) {
  int row = blockIdx.x;
  int t = threadIdx.x;
  const float* xr = x + (size_t)row * 1024;
  f32x4 v = *(const f32x4*)(xr + t * 4);
  float s = v[0] + v[1] + v[2] + v[3];
  float s2 = v[0] * v[0] + v[1] * v[1] + v[2] * v[2] + v[3] * v[3];
#pragma unroll
  for (int off = 1; off < 64; off <<= 1) {
    s += __shfl_xor(s, off);
    s2 += __shfl_xor(s2, off);
  }
  __shared__ float red[8];
  if ((t & 63) == 0) { red[t >> 6] = s; red[4 + (t >> 6)] = s2; }
  __syncthreads();
  s = red[0] + red[1] + red[2] + red[3];
  s2 = red[4] + red[5] + red[6] + red[7];
  float mean = s * (1.0f / 1024.0f);
  float var = fmaxf(s2 * (1.0f / 1024.0f) - mean * mean, 0.0f);
  float rstd = rsqrtf(var + 1e-5f);
  f32x4 gg = *(const f32x4*)(g + t * 4);
  f32x4 bb = *(const f32x4*)(be + t * 4);
  uint2 ww;
  ww.x = pk2((v[0] - mean) * rstd * gg[0] + bb[0], (v[1] - mean) * rstd * gg[1] + bb[1]);
  ww.y = pk2((v[2] - mean) * rstd * gg[2] + bb[2], (v[3] - mean) * rstd * gg[3] + bb[3]);
  *(uint2*)(o + (size_t)row * 1024 + t * 4) = ww;
}

// ---------------- GEMM: C = A(MxK) @ Bt(NxK)^T, 128x128 tile, BK=64, 4 waves
// MODE 0: qkv scatter (+bias, q*0.125) -> bf16 q/k (B,H,N,64); v TRANSPOSED (B,H,64,N)
// MODE 1: +bias+resid(f32) -> f32   (out-proj)
// MODE 2: +bias, exact gelu -> bf16 (ff1)
// MODE 3: +bias+resid(f32) -> f32   (ff2, writes d_out)
template <int MODE>
__global__ __launch_bounds__(256) void k_gemm(const u16* __restrict__ A, const u16* __restrict__ Bt,
                                              int K, int NC,
                                              const float* __restrict__ bias,
                                              const float* __restrict__ resid,
                                              void* __restrict__ o0, void* __restrict__ o1,
                                              void* __restrict__ o2) {
  __shared__ u16 aT[128 * 64];
  __shared__ u16 bT[128 * 64];
  const int lane = threadIdx.x & 63, wave = threadIdx.x >> 6;
  const int tN = blockIdx.x * 128, tM = blockIdx.y * 128;
  const int wm = (wave >> 1) * 64, wn = (wave & 1) * 64;
  const int lm = lane & 15, lh = lane >> 4;
  f32x4 acc[4][4] = {};
  for (int k0 = 0; k0 < K; k0 += 64) {
    __syncthreads();
#pragma unroll
    for (int i = 0; i < 4; ++i) {
      int seg = i * 4 + wave;
      int li = seg * 64 + lane;
      int m = li >> 3, ch = li & 7;
      // pre-swizzled source so linear LDS dest == XOR-swizzled tile
      gload_lds16(A + (size_t)(tM + m) * K + k0 + ((ch ^ (m & 7)) << 3), (void*)(aT + seg * 512));
      gload_lds16(Bt + (size_t)(tN + m) * K + k0 + ((ch ^ (m & 7)) << 3), (void*)(bT + seg * 512));
    }
    __syncthreads();
#pragma unroll
    for (int s = 0; s < 2; ++s) {
      bf16x8 af[4], bfr[4];
#pragma unroll
      for (int i = 0; i < 4; ++i) {
        int m = wm + i * 16 + lm;
        af[i] = *(const bf16x8*)((const char*)aT + m * 128 + (((s * 4 + lh) ^ (m & 7)) << 4));
      }
#pragma unroll
      for (int j = 0; j < 4; ++j) {
        int n = wn + j * 16 + lm;
        bfr[j] = *(const bf16x8*)((const char*)bT + n * 128 + (((s * 4 + lh) ^ (n & 7)) << 4));
      }
#pragma unroll
      for (int i = 0; i < 4; ++i)
#pragma unroll
        for (int j = 0; j < 4; ++j)
          acc[i][j] = __builtin_amdgcn_mfma_f32_16x16x32_bf16(af[i], bfr[j], acc[i][j], 0, 0, 0);
    }
  }
#pragma unroll
  for (int i = 0; i < 4; ++i) {
#pragma unroll
    for (int j = 0; j < 4; ++j) {
      int gn = tN + wn + j * 16 + lm;
      int gm0 = tM + wm + i * 16 + lh * 4;
      float vals[4];
#pragma unroll
      for (int r = 0; r < 4; ++r) vals[r] = acc[i][j][r] + bias[gn];
      if constexpr (MODE == 0) {
        int which = gn >> 10, h = (gn >> 6) & 15, d = gn & 63;
        int b = gm0 >> 11, nn0 = gm0 & 2047;
        if (which == 2) {
          // V transposed: (b,h,d,n) -- packed 8B store (4 consecutive n)
          uint2 w2;
          w2.x = pk2(vals[0], vals[1]);
          w2.y = pk2(vals[2], vals[3]);
          *(uint2*)((u16*)o2 + ((size_t)(b * 16 + h) * 64 + d) * 2048 + nn0) = w2;
        } else {
          u16* dst = which == 0 ? (u16*)o0 : (u16*)o1;
          float sc = which == 0 ? 0.125f : 1.0f;  // fold 1/sqrt(HD) into q
#pragma unroll
          for (int r = 0; r < 4; ++r)
            dst[(((size_t)(b * 16 + h)) * 2048 + nn0 + r) * 64 + d] = f2bf(vals[r] * sc);
        }
      } else if constexpr (MODE == 2) {
#pragma unroll
        for (int r = 0; r < 4; ++r) {
          float gl = 0.5f * vals[r] * (1.0f + erff(vals[r] * 0.70710678118654752f));
          ((u16*)o0)[(size_t)(gm0 + r) * NC + gn] = f2bf(gl);
        }
      } else {
#pragma unroll
        for (int r = 0; r < 4; ++r)
          ((float*)o0)[(size_t)(gm0 + r) * NC + gn] =
              vals[r] + resid[(size_t)(gm0 + r) * NC + gn];
      }
    }
  }
}

// ---------------- full attention (mask vacuous), flash-style, swapped QK^T.
// 512-thread blocks: 8 waves = 2 q-subtiles x 4 k-splits. Grid (32 qtiles, B*H)
// = 1024 blocks -> 4 blocks/CU -> 32 waves/CU (8/SIMD) for latency hiding.
// Each wave: 32 q rows, 512-k quarter, 8 iters of 64k. Splits merged in-block
// via LDS; writes attnb (b, n, h*64+d) directly. No global partials.
__global__ __launch_bounds__(512, 8) void k_attn(const u16* __restrict__ q,
                                                 const u16* __restrict__ k,
                                                 const u16* __restrict__ vt,
                                                 u16* __restrict__ o) {
  __shared__ u16 Ob[2 * 4 * 32 * 66];   // [qsub][ks][q][66] bf16 partial O (pad 66)
  __shared__ float2 Ml[2 * 4 * 32];     // (m, l) per partial row
  const int t = threadIdx.x;
  const int lane = t & 63, wave = t >> 6;
  const int ql = lane & 31, hi = lane >> 5;
  const int qsub = wave & 1, ks = wave >> 1;
  const int bh = blockIdx.y;
  const int q0 = blockIdx.x * 64 + qsub * 32;
  const float C_LOG2E = 1.44269504088896f;

  const u16* qp = q + ((size_t)bh * 2048 + q0 + ql) * 64 + hi * 8;
  bf16x8 qf[4];
#pragma unroll
  for (int dc = 0; dc < 4; ++dc) qf[dc] = *(const bf16x8*)(qp + dc * 16);

  const u16* kbase = k + ((size_t)bh * 2048 + ks * 512 + ql) * 64 + hi * 8;
  const u16* vtp = vt + ((size_t)bh * 64 + ql) * 2048 + ks * 512 + hi * 8;

  f32x16 ot0 = {0, 0, 0, 0, 0, 0, 0, 0, 0, 0, 0, 0, 0, 0, 0, 0};
  f32x16 ot1 = ot0;
  float mrun = -1e30f, lsum = 0.0f;

  for (int it = 0; it < 8; ++it) {
    const int koff = it * 64;
    bf16x8 kf[8];
#pragma unroll
    for (int sub = 0; sub < 2; ++sub)
#pragma unroll
      for (int dc = 0; dc < 4; ++dc)
        kf[sub * 4 + dc] =
            *(const bf16x8*)(kbase + (size_t)(koff + sub * 32) * 64 + dc * 16);
#pragma unroll
    for (int sub = 0; sub < 2; ++sub) {
      f32x16 st = {0, 0, 0, 0, 0, 0, 0, 0, 0, 0, 0, 0, 0, 0, 0, 0};
#pragma unroll
      for (int dc = 0; dc < 4; ++dc)
        st = __builtin_amdgcn_mfma_f32_32x32x16_bf16(kf[sub * 4 + dc], qf[dc], st, 0, 0, 0);
      // issue V^T fragment loads early (in flight during softmax VALU)
      bf16x8 vf[4];
#pragma unroll
      for (int kc = 0; kc < 2; ++kc)
#pragma unroll
        for (int dh = 0; dh < 2; ++dh)
          vf[kc * 2 + dh] =
              *(const bf16x8*)(vtp + (size_t)dh * 32 * 2048 + koff + sub * 32 + kc * 16);
      // online softmax (q-row = lane&31; k-halves across hi). Tree reductions.
      float a8[8];
#pragma unroll
      for (int r = 0; r < 8; ++r) a8[r] = fmaxf(st[2 * r], st[2 * r + 1]);
#pragma unroll
      for (int r = 0; r < 4; ++r) a8[r] = fmaxf(a8[r], a8[r + 4]);
      float smax = fmaxf(fmaxf(a8[0], a8[2]), fmaxf(a8[1], a8[3]));
      smax = fmaxf(smax, __shfl_xor(smax, 32));
      float mnew = fmaxf(mrun, smax);
      if (!__all(smax <= mrun + 8.0f)) {  // defer-max: rescale rarely
        float sf = fexp2((mrun - mnew) * C_LOG2E);
#pragma unroll
        for (int r = 0; r < 16; ++r) { ot0[r] *= sf; ot1[r] *= sf; }
        lsum *= sf;
        mrun = mnew;
      }
      float aa = mrun * C_LOG2E;
      float p[16];
#pragma unroll
      for (int r = 0; r < 16; ++r) p[r] = fexp2(st[r] * C_LOG2E - aa);
      float s8[8];
#pragma unroll
      for (int r = 0; r < 8; ++r) s8[r] = p[2 * r] + p[2 * r + 1];
#pragma unroll
      for (int r = 0; r < 4; ++r) s8[r] = s8[r] + s8[r + 4];
      float ts = (s8[0] + s8[2]) + (s8[1] + s8[3]);
      ts += __shfl_xor(ts, 32);
      lsum += ts;
      // P -> bf16 B-fragments via permlane32_swap, O^T += V^T @ P^T
#pragma unroll
      for (int kc = 0; kc < 2; ++kc) {
        u32 x0 = cvtpk(p[kc * 8 + 0], p[kc * 8 + 1]), x1 = cvtpk(p[kc * 8 + 2], p[kc * 8 + 3]);
        u32 y0 = cvtpk(p[kc * 8 + 4], p[kc * 8 + 5]), y1 = cvtpk(p[kc * 8 + 6], p[kc * 8 + 7]);
        // swap x.hi <-> y.lo: x' = {x.lo, y.lo}, y' = {x.hi, y.hi}
        asm("v_permlane32_swap_b32 %0, %1" : "+v"(x0), "+v"(y0));
        asm("v_permlane32_swap_b32 %0, %1" : "+v"(x1), "+v"(y1));
        union { u32 u[4]; bf16x8 v8; } pf;
        pf.u[0] = x0;
        pf.u[1] = x1;
        pf.u[2] = y0;
        pf.u[3] = y1;
        ot0 = __builtin_amdgcn_mfma_f32_32x32x16_bf16(vf[kc * 2 + 0], pf.v8, ot0, 0, 0, 0);
        ot1 = __builtin_amdgcn_mfma_f32_32x32x16_bf16(vf[kc * 2 + 1], pf.v8, ot1, 0, 0, 0);
      }
    }
  }
  // stage partials to LDS: row = (qsub*4+ks)*32 + ql, padded stride 66 u16
  {
    int row = (qsub * 4 + ks) * 32 + ql;
    u16* ob = &Ob[row * 66];
#pragma unroll
    for (int j = 0; j < 8; ++j) {
      int w = (j & 1) + ((j >> 1) << 2) + hi * 2;  // u32-word index for d(2j)/2
      *(u32*)(ob + 2 * w) = cvtpk(ot0[2 * j], ot0[2 * j + 1]);
      *(u32*)(ob + 2 * (w + 16)) = cvtpk(ot1[2 * j], ot1[2 * j + 1]);
    }
    if (hi == 0) { float2 ml; ml.x = mrun; ml.y = lsum; Ml[row] = ml; }
  }
  __syncthreads();
  // merge 4 k-splits: 512 threads cover 2*32*64 outputs, 8 per thread
  {
    int qs2 = t >> 8, qq = (t >> 3) & 31, j2 = t & 7;
    float2 ml[4];
#pragma unroll
    for (int s = 0; s < 4; ++s) ml[s] = Ml[(qs2 * 4 + s) * 32 + qq];
    float m = fmaxf(fmaxf(ml[0].x, ml[1].x), fmaxf(ml[2].x, ml[3].x));
    float w[4], L = 0.0f;
#pragma unroll
    for (int s = 0; s < 4; ++s) { w[s] = fexp2((ml[s].x - m) * C_LOG2E); L += w[s] * ml[s].y; }
    float acc[8] = {0, 0, 0, 0, 0, 0, 0, 0};
#pragma unroll
    for (int s = 0; s < 4; ++s) {
      const u16* ob = &Ob[((qs2 * 4 + s) * 32 + qq) * 66 + j2 * 8];
#pragma unroll
      for (int i = 0; i < 4; ++i) {
        u32 wv = *(const u32*)(ob + 2 * i);
        acc[2 * i] += w[s] * bf2f((u16)(wv & 0xFFFF));
        acc[2 * i + 1] += w[s] * bf2f((u16)(wv >> 16));
      }
    }
    float inv = 1.0f / L;
    int b = bh >> 4, h = bh & 15;
    int n = blockIdx.x * 64 + qs2 * 32 + qq;
    uint4 wout;
    wout.x = cvtpk(acc[0] * inv, acc[1] * inv);
    wout.y = cvtpk(acc[2] * inv, acc[3] * inv);
    wout.z = cvtpk(acc[4] * inv, acc[5] * inv);
    wout.w = cvtpk(acc[6] * inv, acc[7] * inv);
    *(uint4*)(o + ((size_t)(b * 2048 + n)) * 1024 + h * 64 + j2 * 8) = wout;
  }
}

extern "C" void kernel_launch(void* const* d_in, const int* in_sizes, int n_in,
                              void* d_out, int out_size, void* d_ws, size_t ws_size,
                              hipStream_t stream) {
  const float* x = (const float*)d_in[0];
  // d_in[1] positions: provably irrelevant (mask all-true at N=2048)
  const float* w_qkv = (const float*)d_in[2];
  const float* b_qkv = (const float*)d_in[3];
  const float* w_out = (const float*)d_in[4];
  const float* b_out = (const float*)d_in[5];
  const float* w_ff1 = (const float*)d_in[6];
  const float* b_ff1 = (const float*)d_in[7];
  const float* w_ff2 = (const float*)d_in[8];
  const float* b_ff2 = (const float*)d_in[9];
  const float* g1 = (const float*)d_in[10];
  const float* be1 = (const float*)d_in[11];
  const float* g2 = (const float*)d_in[12];
  const float* be2 = (const float*)d_in[13];
  float* out = (float*)d_out;

  char* wp = (char*)d_ws;
  u16* wqkvT = (u16*)wp; wp += (size_t)3072 * 1024 * 2;
  u16* woutT = (u16*)wp; wp += (size_t)1024 * 1024 * 2;
  u16* wff1T = (u16*)wp; wp += (size_t)4096 * 1024 * 2;
  u16* wff2T = (u16*)wp; wp += (size_t)1024 * 4096 * 2;
  u16* xn    = (u16*)wp; wp += (size_t)4096 * 1024 * 2;   // reused for xn2
  float* x2  = (float*)wp; wp += (size_t)4096 * 1024 * 4;
  u16* qbuf  = (u16*)wp; wp += (size_t)32 * 2048 * 64 * 2;
  u16* kbuf  = (u16*)wp; wp += (size_t)32 * 2048 * 64 * 2;
  u16* vtbuf = (u16*)wp; wp += (size_t)32 * 2048 * 64 * 2;  // V^T (b,h,d,n)
  u16* attnb = (u16*)wp; wp += (size_t)4096 * 1024 * 2;
  u16* ffh   = qbuf;  // alias: ff hidden (33.5MB) reuses q/k/v region after attention

  // weights -> bf16, transposed to (N x K)
  k_transpose_bf16<<<dim3(3072 / 32, 1024 / 32), 256, 0, stream>>>(w_qkv, wqkvT, 1024, 3072);
  k_transpose_bf16<<<dim3(1024 / 32, 1024 / 32), 256, 0, stream>>>(w_out, woutT, 1024, 1024);
  k_transpose_bf16<<<dim3(4096 / 32, 1024 / 32), 256, 0, stream>>>(w_ff1, wff1T, 1024, 4096);
  k_transpose_bf16<<<dim3(1024 / 32, 4096 / 32), 256, 0, stream>>>(w_ff2, wff2T, 4096, 1024);

  k_layernorm<<<4096, 256, 0, stream>>>(x, g1, be1, xn);
  k_gemm<0><<<dim3(24, 32), 256, 0, stream>>>(xn, wqkvT, 1024, 3072, b_qkv, nullptr,
                                              qbuf, kbuf, vtbuf);
  k_attn<<<dim3(32, 32), 512, 0, stream>>>(qbuf, kbuf, vtbuf, attnb);
  k_gemm<1><<<dim3(8, 32), 256, 0, stream>>>(attnb, woutT, 1024, 1024, b_out, x,
                                             x2, nullptr, nullptr);
  k_layernorm<<<4096, 256, 0, stream>>>(x2, g2, be2, xn);
  k_gemm<2><<<dim3(32, 32), 256, 0, stream>>>(xn, wff1T, 1024, 4096, b_ff1, nullptr,
                                              ffh, nullptr, nullptr);
  k_gemm<3><<<dim3(8, 32), 256, 0, stream>>>(ffh, wff2T, 4096, 1024, b_ff2, x2,
                                             out, nullptr, nullptr);
}

// Round 4
// 292.154 us; speedup vs baseline: 3.6108x; 3.6108x over previous
//
#include <hip/hip_runtime.h>
#include <cstdint>
#include <cstddef>

// MLSWA transformer block, B=2 N=2048 D=1024 H=16 HD=64 DFF=4096.
// NOTE: the multi-level window mask is ALL-TRUE for N=2048 (level-2 positions
// span 0..7, window 16) -> plain full attention.

using u16 = unsigned short;
using u32 = unsigned int;

typedef __attribute__((ext_vector_type(8)))  short bf16x8;
typedef __attribute__((ext_vector_type(4)))  float f32x4;
typedef __attribute__((ext_vector_type(16))) float f32x16;

#define DEV __device__ __forceinline__

DEV u16 f2bf(float f) {
  u32 u = __builtin_bit_cast(u32, f);
  u32 r = (u + 0x7FFFu + ((u >> 16) & 1u)) >> 16;
  return (u16)r;
}
DEV float bf2f(u16 u) { return __builtin_bit_cast(float, (u32)u << 16); }
DEV u32 pk2(float a, float b) { return (u32)f2bf(a) | ((u32)f2bf(b) << 16); }
DEV u32 cvtpk(float lo, float hi) {
  u32 r;
  asm("v_cvt_pk_bf16_f32 %0, %1, %2" : "=v"(r) : "v"(lo), "v"(hi));
  return r;
}
DEV float fexp2(float x) { return __builtin_amdgcn_exp2f(x); }

DEV void gload_lds16(const void* g, void* lds) {
  __builtin_amdgcn_global_load_lds(
      (const __attribute__((address_space(1))) u32*)g,
      (__attribute__((address_space(3))) u32*)lds, 16, 0, 0);
}

// ---------------- weight transpose + bf16 convert: in (R x C) f32 -> out (C x R) bf16
__global__ __launch_bounds__(256) void k_transpose_bf16(const float* __restrict__ in,
                                                        u16* __restrict__ out, int R, int C) {
  __shared__ float ts[32][33];
  int n0 = blockIdx.x * 32, r0 = blockIdx.y * 32;
  int t = threadIdx.x;
  int c = t & 31, r = t >> 5; // r in 0..7
#pragma unroll
  for (int j = 0; j < 4; ++j)
    ts[r + 8 * j][c] = in[(size_t)(r0 + r + 8 * j) * C + n0 + c];
  __syncthreads();
#pragma unroll
  for (int j = 0; j < 4; ++j)
    out[(size_t)(n0 + r + 8 * j) * R + r0 + c] = f2bf(ts[c][r + 8 * j]);
}

// ---------------- layernorm: one block per row (D=1024), bf16 out
__global__ __launch_bounds__(256) void k_layernorm(const float* __restrict__ x,
                                                   const float* __restrict__ g,
                                                   const float* __restrict__ be,
                                                   u16* __restrict__ o) {
  int row = blockIdx.x;
  int t = threadIdx.x;
  const float* xr = x + (size_t)row * 1024;
  f32x4 v = *(const f32x4*)(xr + t * 4);
  float s = v[0] + v[1] + v[2] + v[3];
  float s2 = v[0] * v[0] + v[1] * v[1] + v[2] * v[2] + v[3] * v[3];
#pragma unroll
  for (int off = 1; off < 64; off <<= 1) {
    s += __shfl_xor(s, off);
    s2 += __shfl_xor(s2, off);
  }
  __shared__ float red[8];
  if ((t & 63) == 0) { red[t >> 6] = s; red[4 + (t >> 6)] = s2; }
  __syncthreads();
  s = red[0] + red[1] + red[2] + red[3];
  s2 = red[4] + red[5] + red[6] + red[7];
  float mean = s * (1.0f / 1024.0f);
  float var = fmaxf(s2 * (1.0f / 1024.0f) - mean * mean, 0.0f);
  float rstd = rsqrtf(var + 1e-5f);
  f32x4 gg = *(const f32x4*)(g + t * 4);
  f32x4 bb = *(const f32x4*)(be + t * 4);
  uint2 ww;
  ww.x = pk2((v[0] - mean) * rstd * gg[0] + bb[0], (v[1] - mean) * rstd * gg[1] + bb[1]);
  ww.y = pk2((v[2] - mean) * rstd * gg[2] + bb[2], (v[3] - mean) * rstd * gg[3] + bb[3]);
  *(uint2*)(o + (size_t)row * 1024 + t * 4) = ww;
}

// ---------------- GEMM: C = A(MxK) @ Bt(NxK)^T, 128x128 tile, BK=64, 4 waves
// MODE 0: qkv scatter (+bias, q*0.125) -> bf16 q/k (B,H,N,64); v TRANSPOSED (B,H,64,N)
// MODE 1: +bias+resid(f32) -> f32   (out-proj)
// MODE 2: +bias, exact gelu -> bf16 (ff1)
// MODE 3: +bias+resid(f32) -> f32   (ff2, writes d_out)
template <int MODE>
__global__ __launch_bounds__(256) void k_gemm(const u16* __restrict__ A, const u16* __restrict__ Bt,
                                              int K, int NC,
                                              const float* __restrict__ bias,
                                              const float* __restrict__ resid,
                                              void* __restrict__ o0, void* __restrict__ o1,
                                              void* __restrict__ o2) {
  __shared__ u16 aT[128 * 64];
  __shared__ u16 bT[128 * 64];
  const int lane = threadIdx.x & 63, wave = threadIdx.x >> 6;
  const int tN = blockIdx.x * 128, tM = blockIdx.y * 128;
  const int wm = (wave >> 1) * 64, wn = (wave & 1) * 64;
  const int lm = lane & 15, lh = lane >> 4;
  f32x4 acc[4][4] = {};
  for (int k0 = 0; k0 < K; k0 += 64) {
    __syncthreads();
#pragma unroll
    for (int i = 0; i < 4; ++i) {
      int seg = i * 4 + wave;
      int li = seg * 64 + lane;
      int m = li >> 3, ch = li & 7;
      // pre-swizzled source so linear LDS dest == XOR-swizzled tile
      gload_lds16(A + (size_t)(tM + m) * K + k0 + ((ch ^ (m & 7)) << 3), (void*)(aT + seg * 512));
      gload_lds16(Bt + (size_t)(tN + m) * K + k0 + ((ch ^ (m & 7)) << 3), (void*)(bT + seg * 512));
    }
    __syncthreads();
#pragma unroll
    for (int s = 0; s < 2; ++s) {
      bf16x8 af[4], bfr[4];
#pragma unroll
      for (int i = 0; i < 4; ++i) {
        int m = wm + i * 16 + lm;
        af[i] = *(const bf16x8*)((const char*)aT + m * 128 + (((s * 4 + lh) ^ (m & 7)) << 4));
      }
#pragma unroll
      for (int j = 0; j < 4; ++j) {
        int n = wn + j * 16 + lm;
        bfr[j] = *(const bf16x8*)((const char*)bT + n * 128 + (((s * 4 + lh) ^ (n & 7)) << 4));
      }
#pragma unroll
      for (int i = 0; i < 4; ++i)
#pragma unroll
        for (int j = 0; j < 4; ++j)
          acc[i][j] = __builtin_amdgcn_mfma_f32_16x16x32_bf16(af[i], bfr[j], acc[i][j], 0, 0, 0);
    }
  }
#pragma unroll
  for (int i = 0; i < 4; ++i) {
#pragma unroll
    for (int j = 0; j < 4; ++j) {
      int gn = tN + wn + j * 16 + lm;
      int gm0 = tM + wm + i * 16 + lh * 4;
      float vals[4];
#pragma unroll
      for (int r = 0; r < 4; ++r) vals[r] = acc[i][j][r] + bias[gn];
      if constexpr (MODE == 0) {
        int which = gn >> 10, h = (gn >> 6) & 15, d = gn & 63;
        int b = gm0 >> 11, nn0 = gm0 & 2047;
        if (which == 2) {
          // V transposed: (b,h,d,n) -- packed 8B store (4 consecutive n)
          uint2 w2;
          w2.x = pk2(vals[0], vals[1]);
          w2.y = pk2(vals[2], vals[3]);
          *(uint2*)((u16*)o2 + ((size_t)(b * 16 + h) * 64 + d) * 2048 + nn0) = w2;
        } else {
          u16* dst = which == 0 ? (u16*)o0 : (u16*)o1;
          float sc = which == 0 ? 0.125f : 1.0f;  // fold 1/sqrt(HD) into q
#pragma unroll
          for (int r = 0; r < 4; ++r)
            dst[(((size_t)(b * 16 + h)) * 2048 + nn0 + r) * 64 + d] = f2bf(vals[r] * sc);
        }
      } else if constexpr (MODE == 2) {
#pragma unroll
        for (int r = 0; r < 4; ++r) {
          float gl = 0.5f * vals[r] * (1.0f + erff(vals[r] * 0.70710678118654752f));
          ((u16*)o0)[(size_t)(gm0 + r) * NC + gn] = f2bf(gl);
        }
      } else {
#pragma unroll
        for (int r = 0; r < 4; ++r)
          ((float*)o0)[(size_t)(gm0 + r) * NC + gn] =
              vals[r] + resid[(size_t)(gm0 + r) * NC + gn];
      }
    }
  }
}

// ---------------- full attention (mask vacuous), flash-style, swapped QK^T.
// 4 waves x 32 q-rows = 128-q tile; grid (16, B*H) = 512 blocks (2/CU).
// K and V^T staged per 64-key tile into LDS via coalesced global_load_lds
// (pre-swizzled source, linear dest; read back with XOR-swizzled ds_read_b128)
// -- kills the 16B/lane gather pattern that bottlenecked the VMEM line path.
// Double-buffered 2-phase: stage(t+1) issued before compute(t), 1 barrier/iter.
__global__ __launch_bounds__(256) void k_attn(const u16* __restrict__ q,
                                              const u16* __restrict__ k,
                                              const u16* __restrict__ vt,
                                              u16* __restrict__ o) {
  __shared__ u16 KT[2][4096];  // [buf][64 keys x 64 d] swizzled
  __shared__ u16 VT[2][4096];  // [buf][64 d x 64 keys] swizzled
  const int tid = threadIdx.x;
  const int lane = tid & 63, wave = tid >> 6;
  const int ql = lane & 31, hi = lane >> 5;
  const int bh = blockIdx.y;
  const int q0 = blockIdx.x * 128 + wave * 32;
  const float C_LOG2E = 1.44269504088896f;

  const u16* qp = q + ((size_t)bh * 2048 + q0 + ql) * 64 + hi * 8;
  bf16x8 qf[4];
#pragma unroll
  for (int dc = 0; dc < 4; ++dc) qf[dc] = *(const bf16x8*)(qp + dc * 16);

  const u16* kst = k + (size_t)bh * 2048 * 64;
  const u16* vst = vt + (size_t)bh * 64 * 2048;

  f32x16 ot0 = {0, 0, 0, 0, 0, 0, 0, 0, 0, 0, 0, 0, 0, 0, 0, 0};
  f32x16 ot1 = ot0;
  float mrun = -1e30f, lsum = 0.0f;

  // stage tile tl (64 keys) into buffer b: 256 threads x 2 chunks x (K,V)
  auto STAGE = [&](int tl, int b) {
    int kb = tl << 6;
#pragma unroll
    for (int i = 0; i < 2; ++i) {
      int seg = i * 4 + wave;          // wave-uniform LDS segment
      int li = seg * 64 + lane;        // linear 16B-chunk index 0..511
      int row = li >> 3, ch = li & 7;
      int sw = (ch ^ (row & 7)) << 3;  // pre-swizzled source chunk (u16 units)
      gload_lds16(kst + (size_t)(kb + row) * 64 + sw, (void*)&KT[b][seg * 512]);
      gload_lds16(vst + (size_t)row * 2048 + kb + sw, (void*)&VT[b][seg * 512]);
    }
  };

  int cur = 0;
  STAGE(0, 0);
  __syncthreads();  // compiler drains vmcnt before barrier -> tile 0 ready

  for (int tl = 0; tl < 32; ++tl) {
    if (tl < 31) STAGE(tl + 1, cur ^ 1);
#pragma unroll
    for (int sub = 0; sub < 2; ++sub) {
      // K fragments from LDS (swizzled read)
      bf16x8 kf[4];
#pragma unroll
      for (int dc = 0; dc < 4; ++dc)
        kf[dc] = *(const bf16x8*)&KT[cur][((sub * 32 + ql) << 6) +
                                          ((((dc << 1) | hi) ^ (ql & 7)) << 3)];
      // V^T fragments from LDS
      bf16x8 vf[4];
#pragma unroll
      for (int kc = 0; kc < 2; ++kc)
#pragma unroll
        for (int dh = 0; dh < 2; ++dh)
          vf[kc * 2 + dh] =
              *(const bf16x8*)&VT[cur][(((dh << 5) + ql) << 6) +
                                       (((sub * 4 + (kc << 1) + hi) ^ (ql & 7)) << 3)];
      // S^T[k][q] = sum_d K[k][d] Q[q][d]
      f32x16 st = {0, 0, 0, 0, 0, 0, 0, 0, 0, 0, 0, 0, 0, 0, 0, 0};
      __builtin_amdgcn_s_setprio(1);
#pragma unroll
      for (int dc = 0; dc < 4; ++dc)
        st = __builtin_amdgcn_mfma_f32_32x32x16_bf16(kf[dc], qf[dc], st, 0, 0, 0);
      __builtin_amdgcn_s_setprio(0);
      // online softmax (q-row = lane&31; k-halves across hi). Tree reductions.
      float a8[8];
#pragma unroll
      for (int r = 0; r < 8; ++r) a8[r] = fmaxf(st[2 * r], st[2 * r + 1]);
#pragma unroll
      for (int r = 0; r < 4; ++r) a8[r] = fmaxf(a8[r], a8[r + 4]);
      float smax = fmaxf(fmaxf(a8[0], a8[2]), fmaxf(a8[1], a8[3]));
      smax = fmaxf(smax, __shfl_xor(smax, 32));
      float mnew = fmaxf(mrun, smax);
      if (!__all(smax <= mrun + 8.0f)) {  // defer-max: rescale rarely
        float sf = fexp2((mrun - mnew) * C_LOG2E);
#pragma unroll
        for (int r = 0; r < 16; ++r) { ot0[r] *= sf; ot1[r] *= sf; }
        lsum *= sf;
        mrun = mnew;
      }
      float aa = mrun * C_LOG2E;
      float p[16];
#pragma unroll
      for (int r = 0; r < 16; ++r) p[r] = fexp2(st[r] * C_LOG2E - aa);
      float s8[8];
#pragma unroll
      for (int r = 0; r < 8; ++r) s8[r] = p[2 * r] + p[2 * r + 1];
#pragma unroll
      for (int r = 0; r < 4; ++r) s8[r] = s8[r] + s8[r + 4];
      float ts = (s8[0] + s8[2]) + (s8[1] + s8[3]);
      ts += __shfl_xor(ts, 32);
      lsum += ts;
      // P -> bf16 B-fragments via permlane32_swap, O^T += V^T @ P^T
      __builtin_amdgcn_s_setprio(1);
#pragma unroll
      for (int kc = 0; kc < 2; ++kc) {
        u32 x0 = cvtpk(p[kc * 8 + 0], p[kc * 8 + 1]), x1 = cvtpk(p[kc * 8 + 2], p[kc * 8 + 3]);
        u32 y0 = cvtpk(p[kc * 8 + 4], p[kc * 8 + 5]), y1 = cvtpk(p[kc * 8 + 6], p[kc * 8 + 7]);
        // swap x.hi <-> y.lo: x' = {x.lo, y.lo}, y' = {x.hi, y.hi}
        asm("v_permlane32_swap_b32 %0, %1" : "+v"(x0), "+v"(y0));
        asm("v_permlane32_swap_b32 %0, %1" : "+v"(x1), "+v"(y1));
        union { u32 u[4]; bf16x8 v8; } pf;
        pf.u[0] = x0;
        pf.u[1] = x1;
        pf.u[2] = y0;
        pf.u[3] = y1;
        ot0 = __builtin_amdgcn_mfma_f32_32x32x16_bf16(vf[kc * 2 + 0], pf.v8, ot0, 0, 0, 0);
        ot1 = __builtin_amdgcn_mfma_f32_32x32x16_bf16(vf[kc * 2 + 1], pf.v8, ot1, 0, 0, 0);
      }
      __builtin_amdgcn_s_setprio(0);
    }
    __syncthreads();  // all waves done with buf[cur]; stage(t+1) drained
    cur ^= 1;
  }

  float inv = 1.0f / lsum;
  int b = bh >> 4, h = bh & 15;
  size_t ob = ((size_t)b * 2048 + q0 + ql) * 1024 + h * 64;
#pragma unroll
  for (int r = 0; r < 16; ++r) {
    int d = (r & 3) + ((r >> 2) << 3) + hi * 4;
    o[ob + d] = f2bf(ot0[r] * inv);
    o[ob + 32 + d] = f2bf(ot1[r] * inv);
  }
}

extern "C" void kernel_launch(void* const* d_in, const int* in_sizes, int n_in,
                              void* d_out, int out_size, void* d_ws, size_t ws_size,
                              hipStream_t stream) {
  const float* x = (const float*)d_in[0];
  // d_in[1] positions: provably irrelevant (mask all-true at N=2048)
  const float* w_qkv = (const float*)d_in[2];
  const float* b_qkv = (const float*)d_in[3];
  const float* w_out = (const float*)d_in[4];
  const float* b_out = (const float*)d_in[5];
  const float* w_ff1 = (const float*)d_in[6];
  const float* b_ff1 = (const float*)d_in[7];
  const float* w_ff2 = (const float*)d_in[8];
  const float* b_ff2 = (const float*)d_in[9];
  const float* g1 = (const float*)d_in[10];
  const float* be1 = (const float*)d_in[11];
  const float* g2 = (const float*)d_in[12];
  const float* be2 = (const float*)d_in[13];
  float* out = (float*)d_out;

  char* wp = (char*)d_ws;
  u16* wqkvT = (u16*)wp; wp += (size_t)3072 * 1024 * 2;
  u16* woutT = (u16*)wp; wp += (size_t)1024 * 1024 * 2;
  u16* wff1T = (u16*)wp; wp += (size_t)4096 * 1024 * 2;
  u16* wff2T = (u16*)wp; wp += (size_t)1024 * 4096 * 2;
  u16* xn    = (u16*)wp; wp += (size_t)4096 * 1024 * 2;   // reused for xn2
  float* x2  = (float*)wp; wp += (size_t)4096 * 1024 * 4;
  u16* qbuf  = (u16*)wp; wp += (size_t)32 * 2048 * 64 * 2;
  u16* kbuf  = (u16*)wp; wp += (size_t)32 * 2048 * 64 * 2;
  u16* vtbuf = (u16*)wp; wp += (size_t)32 * 2048 * 64 * 2;  // V^T (b,h,d,n)
  u16* attnb = (u16*)wp; wp += (size_t)4096 * 1024 * 2;
  u16* ffh   = qbuf;  // alias: ff hidden (33.5MB) reuses q/k/v region after attention

  // weights -> bf16, transposed to (N x K)
  k_transpose_bf16<<<dim3(3072 / 32, 1024 / 32), 256, 0, stream>>>(w_qkv, wqkvT, 1024, 3072);
  k_transpose_bf16<<<dim3(1024 / 32, 1024 / 32), 256, 0, stream>>>(w_out, woutT, 1024, 1024);
  k_transpose_bf16<<<dim3(4096 / 32, 1024 / 32), 256, 0, stream>>>(w_ff1, wff1T, 1024, 4096);
  k_transpose_bf16<<<dim3(1024 / 32, 4096 / 32), 256, 0, stream>>>(w_ff2, wff2T, 4096, 1024);

  k_layernorm<<<4096, 256, 0, stream>>>(x, g1, be1, xn);
  k_gemm<0><<<dim3(24, 32), 256, 0, stream>>>(xn, wqkvT, 1024, 3072, b_qkv, nullptr,
                                              qbuf, kbuf, vtbuf);
  k_attn<<<dim3(16, 32), 256, 0, stream>>>(qbuf, kbuf, vtbuf, attnb);
  k_gemm<1><<<dim3(8, 32), 256, 0, stream>>>(attnb, woutT, 1024, 1024, b_out, x,
                                             x2, nullptr, nullptr);
  k_layernorm<<<4096, 256, 0, stream>>>(x2, g2, be2, xn);
  k_gemm<2><<<dim3(32, 32), 256, 0, stream>>>(xn, wff1T, 1024, 4096, b_ff1, nullptr,
                                              ffh, nullptr, nullptr);
  k_gemm<3><<<dim3(8, 32), 256, 0, stream>>>(ffh, wff2T, 4096, 1024, b_ff2, x2,
                                             out, nullptr, nullptr);
}

// Round 5
// 279.849 us; speedup vs baseline: 3.7695x; 1.0440x over previous
//
#include <hip/hip_runtime.h>
#include <cstdint>
#include <cstddef>

// MLSWA transformer block, B=2 N=2048 D=1024 H=16 HD=64 DFF=4096.
// NOTE: the multi-level window mask is ALL-TRUE for N=2048 (level-2 positions
// span 0..7, window 16) -> plain full attention.

using u16 = unsigned short;
using u32 = unsigned int;

typedef __attribute__((ext_vector_type(8)))  short bf16x8;
typedef __attribute__((ext_vector_type(4)))  float f32x4;
typedef __attribute__((ext_vector_type(16))) float f32x16;

#define DEV __device__ __forceinline__

DEV u16 f2bf(float f) {
  u32 u = __builtin_bit_cast(u32, f);
  u32 r = (u + 0x7FFFu + ((u >> 16) & 1u)) >> 16;
  return (u16)r;
}
DEV float bf2f(u16 u) { return __builtin_bit_cast(float, (u32)u << 16); }
DEV u32 pk2(float a, float b) { return (u32)f2bf(a) | ((u32)f2bf(b) << 16); }
DEV u32 cvtpk(float lo, float hi) {
  u32 r;
  asm("v_cvt_pk_bf16_f32 %0, %1, %2" : "=v"(r) : "v"(lo), "v"(hi));
  return r;
}
DEV float fexp2(float x) { return __builtin_amdgcn_exp2f(x); }

DEV void gload_lds16(const void* g, void* lds) {
  __builtin_amdgcn_global_load_lds(
      (const __attribute__((address_space(1))) u32*)g,
      (__attribute__((address_space(3))) u32*)lds, 16, 0, 0);
}

// ---------------- weight transpose + bf16 convert: in (R x C) f32 -> out (C x R) bf16
__global__ __launch_bounds__(256) void k_transpose_bf16(const float* __restrict__ in,
                                                        u16* __restrict__ out, int R, int C) {
  __shared__ float ts[32][33];
  int n0 = blockIdx.x * 32, r0 = blockIdx.y * 32;
  int t = threadIdx.x;
  int c = t & 31, r = t >> 5; // r in 0..7
#pragma unroll
  for (int j = 0; j < 4; ++j)
    ts[r + 8 * j][c] = in[(size_t)(r0 + r + 8 * j) * C + n0 + c];
  __syncthreads();
#pragma unroll
  for (int j = 0; j < 4; ++j)
    out[(size_t)(n0 + r + 8 * j) * R + r0 + c] = f2bf(ts[c][r + 8 * j]);
}

// ---------------- layernorm: one block per row (D=1024), bf16 out
__global__ __launch_bounds__(256) void k_layernorm(const float* __restrict__ x,
                                                   const float* __restrict__ g,
                                                   const float* __restrict__ be,
                                                   u16* __restrict__ o) {
  int row = blockIdx.x;
  int t = threadIdx.x;
  const float* xr = x + (size_t)row * 1024;
  f32x4 v = *(const f32x4*)(xr + t * 4);
  float s = v[0] + v[1] + v[2] + v[3];
  float s2 = v[0] * v[0] + v[1] * v[1] + v[2] * v[2] + v[3] * v[3];
#pragma unroll
  for (int off = 1; off < 64; off <<= 1) {
    s += __shfl_xor(s, off);
    s2 += __shfl_xor(s2, off);
  }
  __shared__ float red[8];
  if ((t & 63) == 0) { red[t >> 6] = s; red[4 + (t >> 6)] = s2; }
  __syncthreads();
  s = red[0] + red[1] + red[2] + red[3];
  s2 = red[4] + red[5] + red[6] + red[7];
  float mean = s * (1.0f / 1024.0f);
  float var = fmaxf(s2 * (1.0f / 1024.0f) - mean * mean, 0.0f);
  float rstd = rsqrtf(var + 1e-5f);
  f32x4 gg = *(const f32x4*)(g + t * 4);
  f32x4 bb = *(const f32x4*)(be + t * 4);
  uint2 ww;
  ww.x = pk2((v[0] - mean) * rstd * gg[0] + bb[0], (v[1] - mean) * rstd * gg[1] + bb[1]);
  ww.y = pk2((v[2] - mean) * rstd * gg[2] + bb[2], (v[3] - mean) * rstd * gg[3] + bb[3]);
  *(uint2*)(o + (size_t)row * 1024 + t * 4) = ww;
}

// ---------------- GEMM: C = A(MxK) @ Bt(NxK)^T, 128x128 tile, BK=64, 4 waves.
// Double-buffered LDS + counted vmcnt(8) (T4): tile t+1's global_load_lds stay
// in flight across the barrier; raw s_barrier (no compiler vmcnt(0) drain).
// XCD-aware swizzle (T1): consecutive-in-XCD blocks share the A-panel.
// MODE 0: qkv scatter (+bias, q*0.125) -> bf16 q/k (B,H,N,64); v TRANSPOSED (B,H,64,N)
// MODE 1: +bias+resid(f32) -> f32   (out-proj)
// MODE 2: +bias, exact gelu -> bf16 (ff1)
// MODE 3: +bias+resid(f32) -> f32   (ff2, writes d_out)
template <int MODE>
__global__ __launch_bounds__(256) void k_gemm(const u16* __restrict__ A, const u16* __restrict__ Bt,
                                              int K, int NC,
                                              const float* __restrict__ bias,
                                              const float* __restrict__ resid,
                                              void* __restrict__ o0, void* __restrict__ o1,
                                              void* __restrict__ o2) {
  __shared__ u16 aT[2][128 * 64];
  __shared__ u16 bT[2][128 * 64];
  const int lane = threadIdx.x & 63, wave = threadIdx.x >> 6;
  // XCD swizzle: blocks dealt round-robin to 8 XCDs; give each XCD a
  // contiguous x-fastest range so same-A-panel blocks share one L2.
  const int nwg = gridDim.x * gridDim.y;
  const int id = blockIdx.y * gridDim.x + blockIdx.x;
  const int wg = (id & 7) * (nwg >> 3) + (id >> 3);
  const int tN = (wg % gridDim.x) * 128, tM = (wg / gridDim.x) * 128;
  const int wm = (wave >> 1) * 64, wn = (wave & 1) * 64;
  const int lm = lane & 15, lh = lane >> 4;
  f32x4 acc[4][4] = {};

  auto STAGE = [&](int k0, int b) {
#pragma unroll
    for (int i = 0; i < 4; ++i) {
      int seg = i * 4 + wave;
      int li = seg * 64 + lane;
      int m = li >> 3, ch = li & 7;
      // pre-swizzled source so linear LDS dest == XOR-swizzled tile
      gload_lds16(A + (size_t)(tM + m) * K + k0 + ((ch ^ (m & 7)) << 3),
                  (void*)(aT[b] + seg * 512));
      gload_lds16(Bt + (size_t)(tN + m) * K + k0 + ((ch ^ (m & 7)) << 3),
                  (void*)(bT[b] + seg * 512));
    }
  };

  const int nk = K >> 6;
  STAGE(0, 0);
  for (int t = 0; t < nk; ++t) {
    const int cur = t & 1;
    if (t + 1 < nk) {
      STAGE((t + 1) << 6, cur ^ 1);
      asm volatile("s_waitcnt vmcnt(8)" ::: "memory");  // tile t (my 8) retired
    } else {
      asm volatile("s_waitcnt vmcnt(0)" ::: "memory");
    }
    __builtin_amdgcn_s_barrier();  // all waves' tile-t loads now in LDS
#pragma unroll
    for (int s = 0; s < 2; ++s) {
      bf16x8 af[4], bfr[4];
#pragma unroll
      for (int i = 0; i < 4; ++i) {
        int m = wm + i * 16 + lm;
        af[i] = *(const bf16x8*)((const char*)aT[cur] + m * 128 +
                                 (((s * 4 + lh) ^ (m & 7)) << 4));
      }
#pragma unroll
      for (int j = 0; j < 4; ++j) {
        int n = wn + j * 16 + lm;
        bfr[j] = *(const bf16x8*)((const char*)bT[cur] + n * 128 +
                                  (((s * 4 + lh) ^ (n & 7)) << 4));
      }
      __builtin_amdgcn_s_setprio(1);
#pragma unroll
      for (int i = 0; i < 4; ++i)
#pragma unroll
        for (int j = 0; j < 4; ++j)
          acc[i][j] = __builtin_amdgcn_mfma_f32_16x16x32_bf16(af[i], bfr[j], acc[i][j], 0, 0, 0);
      __builtin_amdgcn_s_setprio(0);
    }
    __builtin_amdgcn_s_barrier();  // reads of buf[cur] done before overwrite
  }
#pragma unroll
  for (int i = 0; i < 4; ++i) {
#pragma unroll
    for (int j = 0; j < 4; ++j) {
      int gn = tN + wn + j * 16 + lm;
      int gm0 = tM + wm + i * 16 + lh * 4;
      float vals[4];
#pragma unroll
      for (int r = 0; r < 4; ++r) vals[r] = acc[i][j][r] + bias[gn];
      if constexpr (MODE == 0) {
        int which = gn >> 10, h = (gn >> 6) & 15, d = gn & 63;
        int b = gm0 >> 11, nn0 = gm0 & 2047;
        if (which == 2) {
          // V transposed: (b,h,d,n) -- packed 8B store (4 consecutive n)
          uint2 w2;
          w2.x = pk2(vals[0], vals[1]);
          w2.y = pk2(vals[2], vals[3]);
          *(uint2*)((u16*)o2 + ((size_t)(b * 16 + h) * 64 + d) * 2048 + nn0) = w2;
        } else {
          u16* dst = which == 0 ? (u16*)o0 : (u16*)o1;
          float sc = which == 0 ? 0.125f : 1.0f;  // fold 1/sqrt(HD) into q
#pragma unroll
          for (int r = 0; r < 4; ++r)
            dst[(((size_t)(b * 16 + h)) * 2048 + nn0 + r) * 64 + d] = f2bf(vals[r] * sc);
        }
      } else if constexpr (MODE == 2) {
#pragma unroll
        for (int r = 0; r < 4; ++r) {
          float gl = 0.5f * vals[r] * (1.0f + erff(vals[r] * 0.70710678118654752f));
          ((u16*)o0)[(size_t)(gm0 + r) * NC + gn] = f2bf(gl);
        }
      } else {
#pragma unroll
        for (int r = 0; r < 4; ++r)
          ((float*)o0)[(size_t)(gm0 + r) * NC + gn] =
              vals[r] + resid[(size_t)(gm0 + r) * NC + gn];
      }
    }
  }
}

// ---------------- full attention (mask vacuous), flash-style, swapped QK^T.
// 4 waves x 32 q-rows = 128-q tile; grid (16, B*H) = 512 blocks (2/CU).
// K and V^T staged per 64-key tile into LDS via coalesced global_load_lds.
__global__ __launch_bounds__(256) void k_attn(const u16* __restrict__ q,
                                              const u16* __restrict__ k,
                                              const u16* __restrict__ vt,
                                              u16* __restrict__ o) {
  __shared__ u16 KT[2][4096];  // [buf][64 keys x 64 d] swizzled
  __shared__ u16 VT[2][4096];  // [buf][64 d x 64 keys] swizzled
  const int tid = threadIdx.x;
  const int lane = tid & 63, wave = tid >> 6;
  const int ql = lane & 31, hi = lane >> 5;
  const int bh = blockIdx.y;
  const int q0 = blockIdx.x * 128 + wave * 32;
  const float C_LOG2E = 1.44269504088896f;

  const u16* qp = q + ((size_t)bh * 2048 + q0 + ql) * 64 + hi * 8;
  bf16x8 qf[4];
#pragma unroll
  for (int dc = 0; dc < 4; ++dc) qf[dc] = *(const bf16x8*)(qp + dc * 16);

  const u16* kst = k + (size_t)bh * 2048 * 64;
  const u16* vst = vt + (size_t)bh * 64 * 2048;

  f32x16 ot0 = {0, 0, 0, 0, 0, 0, 0, 0, 0, 0, 0, 0, 0, 0, 0, 0};
  f32x16 ot1 = ot0;
  float mrun = -1e30f, lsum = 0.0f;

  // stage tile tl (64 keys) into buffer b: 256 threads x 2 chunks x (K,V)
  auto STAGE = [&](int tl, int b) {
    int kb = tl << 6;
#pragma unroll
    for (int i = 0; i < 2; ++i) {
      int seg = i * 4 + wave;          // wave-uniform LDS segment
      int li = seg * 64 + lane;        // linear 16B-chunk index 0..511
      int row = li >> 3, ch = li & 7;
      int sw = (ch ^ (row & 7)) << 3;  // pre-swizzled source chunk (u16 units)
      gload_lds16(kst + (size_t)(kb + row) * 64 + sw, (void*)&KT[b][seg * 512]);
      gload_lds16(vst + (size_t)row * 2048 + kb + sw, (void*)&VT[b][seg * 512]);
    }
  };

  int cur = 0;
  STAGE(0, 0);
  __syncthreads();  // compiler drains vmcnt before barrier -> tile 0 ready

  for (int tl = 0; tl < 32; ++tl) {
    if (tl < 31) STAGE(tl + 1, cur ^ 1);
#pragma unroll
    for (int sub = 0; sub < 2; ++sub) {
      // K fragments from LDS (swizzled read)
      bf16x8 kf[4];
#pragma unroll
      for (int dc = 0; dc < 4; ++dc)
        kf[dc] = *(const bf16x8*)&KT[cur][((sub * 32 + ql) << 6) +
                                          ((((dc << 1) | hi) ^ (ql & 7)) << 3)];
      // V^T fragments from LDS
      bf16x8 vf[4];
#pragma unroll
      for (int kc = 0; kc < 2; ++kc)
#pragma unroll
        for (int dh = 0; dh < 2; ++dh)
          vf[kc * 2 + dh] =
              *(const bf16x8*)&VT[cur][(((dh << 5) + ql) << 6) +
                                       (((sub * 4 + (kc << 1) + hi) ^ (ql & 7)) << 3)];
      // S^T[k][q] = sum_d K[k][d] Q[q][d]
      f32x16 st = {0, 0, 0, 0, 0, 0, 0, 0, 0, 0, 0, 0, 0, 0, 0, 0};
      __builtin_amdgcn_s_setprio(1);
#pragma unroll
      for (int dc = 0; dc < 4; ++dc)
        st = __builtin_amdgcn_mfma_f32_32x32x16_bf16(kf[dc], qf[dc], st, 0, 0, 0);
      __builtin_amdgcn_s_setprio(0);
      // online softmax (q-row = lane&31; k-halves across hi). Tree reductions.
      float a8[8];
#pragma unroll
      for (int r = 0; r < 8; ++r) a8[r] = fmaxf(st[2 * r], st[2 * r + 1]);
#pragma unroll
      for (int r = 0; r < 4; ++r) a8[r] = fmaxf(a8[r], a8[r + 4]);
      float smax = fmaxf(fmaxf(a8[0], a8[2]), fmaxf(a8[1], a8[3]));
      smax = fmaxf(smax, __shfl_xor(smax, 32));
      float mnew = fmaxf(mrun, smax);
      if (!__all(smax <= mrun + 8.0f)) {  // defer-max: rescale rarely
        float sf = fexp2((mrun - mnew) * C_LOG2E);
#pragma unroll
        for (int r = 0; r < 16; ++r) { ot0[r] *= sf; ot1[r] *= sf; }
        lsum *= sf;
        mrun = mnew;
      }
      float aa = mrun * C_LOG2E;
      float p[16];
#pragma unroll
      for (int r = 0; r < 16; ++r) p[r] = fexp2(st[r] * C_LOG2E - aa);
      float s8[8];
#pragma unroll
      for (int r = 0; r < 8; ++r) s8[r] = p[2 * r] + p[2 * r + 1];
#pragma unroll
      for (int r = 0; r < 4; ++r) s8[r] = s8[r] + s8[r + 4];
      float ts = (s8[0] + s8[2]) + (s8[1] + s8[3]);
      ts += __shfl_xor(ts, 32);
      lsum += ts;
      // P -> bf16 B-fragments via permlane32_swap, O^T += V^T @ P^T
      __builtin_amdgcn_s_setprio(1);
#pragma unroll
      for (int kc = 0; kc < 2; ++kc) {
        u32 x0 = cvtpk(p[kc * 8 + 0], p[kc * 8 + 1]), x1 = cvtpk(p[kc * 8 + 2], p[kc * 8 + 3]);
        u32 y0 = cvtpk(p[kc * 8 + 4], p[kc * 8 + 5]), y1 = cvtpk(p[kc * 8 + 6], p[kc * 8 + 7]);
        // swap x.hi <-> y.lo: x' = {x.lo, y.lo}, y' = {x.hi, y.hi}
        asm("v_permlane32_swap_b32 %0, %1" : "+v"(x0), "+v"(y0));
        asm("v_permlane32_swap_b32 %0, %1" : "+v"(x1), "+v"(y1));
        union { u32 u[4]; bf16x8 v8; } pf;
        pf.u[0] = x0;
        pf.u[1] = x1;
        pf.u[2] = y0;
        pf.u[3] = y1;
        ot0 = __builtin_amdgcn_mfma_f32_32x32x16_bf16(vf[kc * 2 + 0], pf.v8, ot0, 0, 0, 0);
        ot1 = __builtin_amdgcn_mfma_f32_32x32x16_bf16(vf[kc * 2 + 1], pf.v8, ot1, 0, 0, 0);
      }
      __builtin_amdgcn_s_setprio(0);
    }
    __syncthreads();  // all waves done with buf[cur]; stage(t+1) drained
    cur ^= 1;
  }

  float inv = 1.0f / lsum;
  int b = bh >> 4, h = bh & 15;
  size_t ob = ((size_t)b * 2048 + q0 + ql) * 1024 + h * 64;
#pragma unroll
  for (int r = 0; r < 16; ++r) {
    int d = (r & 3) + ((r >> 2) << 3) + hi * 4;
    o[ob + d] = f2bf(ot0[r] * inv);
    o[ob + 32 + d] = f2bf(ot1[r] * inv);
  }
}

extern "C" void kernel_launch(void* const* d_in, const int* in_sizes, int n_in,
                              void* d_out, int out_size, void* d_ws, size_t ws_size,
                              hipStream_t stream) {
  const float* x = (const float*)d_in[0];
  // d_in[1] positions: provably irrelevant (mask all-true at N=2048)
  const float* w_qkv = (const float*)d_in[2];
  const float* b_qkv = (const float*)d_in[3];
  const float* w_out = (const float*)d_in[4];
  const float* b_out = (const float*)d_in[5];
  const float* w_ff1 = (const float*)d_in[6];
  const float* b_ff1 = (const float*)d_in[7];
  const float* w_ff2 = (const float*)d_in[8];
  const float* b_ff2 = (const float*)d_in[9];
  const float* g1 = (const float*)d_in[10];
  const float* be1 = (const float*)d_in[11];
  const float* g2 = (const float*)d_in[12];
  const float* be2 = (const float*)d_in[13];
  float* out = (float*)d_out;

  char* wp = (char*)d_ws;
  u16* wqkvT = (u16*)wp; wp += (size_t)3072 * 1024 * 2;
  u16* woutT = (u16*)wp; wp += (size_t)1024 * 1024 * 2;
  u16* wff1T = (u16*)wp; wp += (size_t)4096 * 1024 * 2;
  u16* wff2T = (u16*)wp; wp += (size_t)1024 * 4096 * 2;
  u16* xn    = (u16*)wp; wp += (size_t)4096 * 1024 * 2;   // reused for xn2
  float* x2  = (float*)wp; wp += (size_t)4096 * 1024 * 4;
  u16* qbuf  = (u16*)wp; wp += (size_t)32 * 2048 * 64 * 2;
  u16* kbuf  = (u16*)wp; wp += (size_t)32 * 2048 * 64 * 2;
  u16* vtbuf = (u16*)wp; wp += (size_t)32 * 2048 * 64 * 2;  // V^T (b,h,d,n)
  u16* attnb = (u16*)wp; wp += (size_t)4096 * 1024 * 2;
  u16* ffh   = qbuf;  // alias: ff hidden (33.5MB) reuses q/k/v region after attention

  // weights -> bf16, transposed to (N x K)
  k_transpose_bf16<<<dim3(3072 / 32, 1024 / 32), 256, 0, stream>>>(w_qkv, wqkvT, 1024, 3072);
  k_transpose_bf16<<<dim3(1024 / 32, 1024 / 32), 256, 0, stream>>>(w_out, woutT, 1024, 1024);
  k_transpose_bf16<<<dim3(4096 / 32, 1024 / 32), 256, 0, stream>>>(w_ff1, wff1T, 1024, 4096);
  k_transpose_bf16<<<dim3(1024 / 32, 4096 / 32), 256, 0, stream>>>(w_ff2, wff2T, 4096, 1024);

  k_layernorm<<<4096, 256, 0, stream>>>(x, g1, be1, xn);
  k_gemm<0><<<dim3(24, 32), 256, 0, stream>>>(xn, wqkvT, 1024, 3072, b_qkv, nullptr,
                                              qbuf, kbuf, vtbuf);
  k_attn<<<dim3(16, 32), 256, 0, stream>>>(qbuf, kbuf, vtbuf, attnb);
  k_gemm<1><<<dim3(8, 32), 256, 0, stream>>>(attnb, woutT, 1024, 1024, b_out, x,
                                             x2, nullptr, nullptr);
  k_layernorm<<<4096, 256, 0, stream>>>(x2, g2, be2, xn);
  k_gemm<2><<<dim3(32, 32), 256, 0, stream>>>(xn, wff1T, 1024, 4096, b_ff1, nullptr,
                                              ffh, nullptr, nullptr);
  k_gemm<3><<<dim3(8, 32), 256, 0, stream>>>(ffh, wff2T, 4096, 1024, b_ff2, x2,
                                             out, nullptr, nullptr);
}

// Round 6
// 268.498 us; speedup vs baseline: 3.9289x; 1.0423x over previous
//
#include <hip/hip_runtime.h>
#include <cstdint>
#include <cstddef>

// MLSWA transformer block, B=2 N=2048 D=1024 H=16 HD=64 DFF=4096.
// NOTE: the multi-level window mask is ALL-TRUE for N=2048 (level-2 positions
// span 0..7, window 16) -> plain full attention.

using u16 = unsigned short;
using u32 = unsigned int;

typedef __attribute__((ext_vector_type(8)))  short bf16x8;
typedef __attribute__((ext_vector_type(4)))  float f32x4;
typedef __attribute__((ext_vector_type(16))) float f32x16;

#define DEV __device__ __forceinline__

DEV u16 f2bf(float f) {
  u32 u = __builtin_bit_cast(u32, f);
  u32 r = (u + 0x7FFFu + ((u >> 16) & 1u)) >> 16;
  return (u16)r;
}
DEV float bf2f(u16 u) { return __builtin_bit_cast(float, (u32)u << 16); }
DEV u32 pk2(float a, float b) { return (u32)f2bf(a) | ((u32)f2bf(b) << 16); }
DEV u32 cvtpk(float lo, float hi) {
  u32 r;
  asm("v_cvt_pk_bf16_f32 %0, %1, %2" : "=v"(r) : "v"(lo), "v"(hi));
  return r;
}
DEV float fexp2(float x) { return __builtin_amdgcn_exp2f(x); }

DEV void gload_lds16(const void* g, void* lds) {
  __builtin_amdgcn_global_load_lds(
      (const __attribute__((address_space(1))) u32*)g,
      (__attribute__((address_space(3))) u32*)lds, 16, 0, 0);
}

// ---------------- weight transpose + bf16 convert: in (R x C) f32 -> out (C x R) bf16
__global__ __launch_bounds__(256) void k_transpose_bf16(const float* __restrict__ in,
                                                        u16* __restrict__ out, int R, int C) {
  __shared__ float ts[32][33];
  int n0 = blockIdx.x * 32, r0 = blockIdx.y * 32;
  int t = threadIdx.x;
  int c = t & 31, r = t >> 5; // r in 0..7
#pragma unroll
  for (int j = 0; j < 4; ++j)
    ts[r + 8 * j][c] = in[(size_t)(r0 + r + 8 * j) * C + n0 + c];
  __syncthreads();
#pragma unroll
  for (int j = 0; j < 4; ++j)
    out[(size_t)(n0 + r + 8 * j) * R + r0 + c] = f2bf(ts[c][r + 8 * j]);
}

// ---------------- layernorm: one block per row (D=1024), bf16 out
__global__ __launch_bounds__(256) void k_layernorm(const float* __restrict__ x,
                                                   const float* __restrict__ g,
                                                   const float* __restrict__ be,
                                                   u16* __restrict__ o) {
  int row = blockIdx.x;
  int t = threadIdx.x;
  const float* xr = x + (size_t)row * 1024;
  f32x4 v = *(const f32x4*)(xr + t * 4);
  float s = v[0] + v[1] + v[2] + v[3];
  float s2 = v[0] * v[0] + v[1] * v[1] + v[2] * v[2] + v[3] * v[3];
#pragma unroll
  for (int off = 1; off < 64; off <<= 1) {
    s += __shfl_xor(s, off);
    s2 += __shfl_xor(s2, off);
  }
  __shared__ float red[8];
  if ((t & 63) == 0) { red[t >> 6] = s; red[4 + (t >> 6)] = s2; }
  __syncthreads();
  s = red[0] + red[1] + red[2] + red[3];
  s2 = red[4] + red[5] + red[6] + red[7];
  float mean = s * (1.0f / 1024.0f);
  float var = fmaxf(s2 * (1.0f / 1024.0f) - mean * mean, 0.0f);
  float rstd = rsqrtf(var + 1e-5f);
  f32x4 gg = *(const f32x4*)(g + t * 4);
  f32x4 bb = *(const f32x4*)(be + t * 4);
  uint2 ww;
  ww.x = pk2((v[0] - mean) * rstd * gg[0] + bb[0], (v[1] - mean) * rstd * gg[1] + bb[1]);
  ww.y = pk2((v[2] - mean) * rstd * gg[2] + bb[2], (v[3] - mean) * rstd * gg[3] + bb[3]);
  *(uint2*)(o + (size_t)row * 1024 + t * 4) = ww;
}

// ---------------- GEMM: C = A(MxK) @ Bt(NxK)^T, 128x128 tile, BK=64.
// m97 structure: single-buffered LDS per K-group, 2 barriers/K-step, occupancy
// provides the overlap (m114). XCD-aware block swizzle (T1).
// SPLIT=1: 256 threads, 4 waves.
// SPLIT=2: 512 threads = 2 K-groups x 4 waves; each group owns 32KB LDS and
//   half the K range (barrier counts align across groups); group 1 dumps its
//   f32 acc into the dead staging LDS at the end, group 0 merges + epilogue.
//   -> grid stays (N/128,M/128) but waves/CU doubles, no extra HBM traffic.
// MODE 0: qkv scatter (+bias, q*0.125) -> bf16 q/k (B,H,N,64); v TRANSPOSED (B,H,64,N)
// MODE 1: +bias+resid(f32) -> f32   (out-proj)
// MODE 2: +bias, exact gelu -> bf16 (ff1)
// MODE 3: +bias+resid(f32) -> f32   (ff2, writes d_out)
template <int MODE, int SPLIT>
__global__ __launch_bounds__(SPLIT * 256) void k_gemm(
    const u16* __restrict__ A, const u16* __restrict__ Bt, int K, int NC,
    const float* __restrict__ bias, const float* __restrict__ resid,
    void* __restrict__ o0, void* __restrict__ o1, void* __restrict__ o2) {
  __shared__ u16 tiles[SPLIT][2][128 * 64];  // [group][a/b][tile]
  const int lane = threadIdx.x & 63, wave = threadIdx.x >> 6;
  const int group = (SPLIT == 2) ? (wave >> 2) : 0;
  const int wv = wave & 3;
  // XCD swizzle: blocks dealt round-robin to 8 XCDs; give each XCD a
  // contiguous x-fastest range so same-A-panel blocks share one L2.
  const int nwg = gridDim.x * gridDim.y;
  const int id = blockIdx.y * gridDim.x + blockIdx.x;
  const int wg = (id & 7) * (nwg >> 3) + (id >> 3);
  const int tN = (wg % gridDim.x) * 128, tM = (wg / gridDim.x) * 128;
  const int wm = (wv >> 1) * 64, wn = (wv & 1) * 64;
  const int lm = lane & 15, lh = lane >> 4;
  const int K2 = K / SPLIT;
  const int kbase = group * K2;
  f32x4 acc[4][4] = {};

  auto STAGE = [&](int k0) {
#pragma unroll
    for (int i = 0; i < 4; ++i) {
      int seg = i * 4 + wv;
      int li = seg * 64 + lane;
      int m = li >> 3, ch = li & 7;
      // pre-swizzled source so linear LDS dest == XOR-swizzled tile
      gload_lds16(A + (size_t)(tM + m) * K + kbase + k0 + ((ch ^ (m & 7)) << 3),
                  (void*)(tiles[group][0] + seg * 512));
      gload_lds16(Bt + (size_t)(tN + m) * K + kbase + k0 + ((ch ^ (m & 7)) << 3),
                  (void*)(tiles[group][1] + seg * 512));
    }
  };

  const int nk = K2 >> 6;
  for (int t = 0; t < nk; ++t) {
    __syncthreads();  // previous compute done before overwrite
    STAGE(t << 6);
    __syncthreads();  // vmcnt drained by compiler -> tile in LDS
#pragma unroll
    for (int s = 0; s < 2; ++s) {
      bf16x8 af[4], bfr[4];
#pragma unroll
      for (int i = 0; i < 4; ++i) {
        int m = wm + i * 16 + lm;
        af[i] = *(const bf16x8*)((const char*)tiles[group][0] + m * 128 +
                                 (((s * 4 + lh) ^ (m & 7)) << 4));
      }
#pragma unroll
      for (int j = 0; j < 4; ++j) {
        int n = wn + j * 16 + lm;
        bfr[j] = *(const bf16x8*)((const char*)tiles[group][1] + n * 128 +
                                  (((s * 4 + lh) ^ (n & 7)) << 4));
      }
#pragma unroll
      for (int i = 0; i < 4; ++i)
#pragma unroll
        for (int j = 0; j < 4; ++j)
          acc[i][j] = __builtin_amdgcn_mfma_f32_16x16x32_bf16(af[i], bfr[j], acc[i][j], 0, 0, 0);
    }
  }

  if constexpr (SPLIT == 2) {
    // merge group 1's accumulator into group 0 via the dead staging LDS (64KB)
    float* comb = (float*)tiles;
    __syncthreads();
    if (group == 1) {
#pragma unroll
      for (int i = 0; i < 4; ++i)
#pragma unroll
        for (int j = 0; j < 4; ++j)
          *(f32x4*)&comb[(i * 4 + j) * 1024 + wv * 256 + lane * 4] = acc[i][j];
    }
    __syncthreads();
    if (group == 1) return;
#pragma unroll
    for (int i = 0; i < 4; ++i)
#pragma unroll
      for (int j = 0; j < 4; ++j) {
        f32x4 other = *(const f32x4*)&comb[(i * 4 + j) * 1024 + wv * 256 + lane * 4];
#pragma unroll
        for (int r = 0; r < 4; ++r) acc[i][j][r] += other[r];
      }
  }

#pragma unroll
  for (int i = 0; i < 4; ++i) {
#pragma unroll
    for (int j = 0; j < 4; ++j) {
      int gn = tN + wn + j * 16 + lm;
      int gm0 = tM + wm + i * 16 + lh * 4;
      float vals[4];
#pragma unroll
      for (int r = 0; r < 4; ++r) vals[r] = acc[i][j][r] + bias[gn];
      if constexpr (MODE == 0) {
        int which = gn >> 10, h = (gn >> 6) & 15, d = gn & 63;
        int b = gm0 >> 11, nn0 = gm0 & 2047;
        if (which == 2) {
          // V transposed: (b,h,d,n) -- packed 8B store (4 consecutive n)
          uint2 w2;
          w2.x = pk2(vals[0], vals[1]);
          w2.y = pk2(vals[2], vals[3]);
          *(uint2*)((u16*)o2 + ((size_t)(b * 16 + h) * 64 + d) * 2048 + nn0) = w2;
        } else {
          u16* dst = which == 0 ? (u16*)o0 : (u16*)o1;
          float sc = which == 0 ? 0.125f : 1.0f;  // fold 1/sqrt(HD) into q
#pragma unroll
          for (int r = 0; r < 4; ++r)
            dst[(((size_t)(b * 16 + h)) * 2048 + nn0 + r) * 64 + d] = f2bf(vals[r] * sc);
        }
      } else if constexpr (MODE == 2) {
#pragma unroll
        for (int r = 0; r < 4; ++r) {
          float gl = 0.5f * vals[r] * (1.0f + erff(vals[r] * 0.70710678118654752f));
          ((u16*)o0)[(size_t)(gm0 + r) * NC + gn] = f2bf(gl);
        }
      } else {
#pragma unroll
        for (int r = 0; r < 4; ++r)
          ((float*)o0)[(size_t)(gm0 + r) * NC + gn] =
              vals[r] + resid[(size_t)(gm0 + r) * NC + gn];
      }
    }
  }
}

// ---------------- full attention (mask vacuous), flash-style, swapped QK^T.
// 4 waves x 32 q-rows = 128-q tile; grid (16, B*H) = 512 blocks (2/CU).
// K and V^T staged per 64-key tile into LDS via coalesced global_load_lds.
__global__ __launch_bounds__(256) void k_attn(const u16* __restrict__ q,
                                              const u16* __restrict__ k,
                                              const u16* __restrict__ vt,
                                              u16* __restrict__ o) {
  __shared__ u16 KT[2][4096];  // [buf][64 keys x 64 d] swizzled
  __shared__ u16 VT[2][4096];  // [buf][64 d x 64 keys] swizzled
  const int tid = threadIdx.x;
  const int lane = tid & 63, wave = tid >> 6;
  const int ql = lane & 31, hi = lane >> 5;
  const int bh = blockIdx.y;
  const int q0 = blockIdx.x * 128 + wave * 32;
  const float C_LOG2E = 1.44269504088896f;

  const u16* qp = q + ((size_t)bh * 2048 + q0 + ql) * 64 + hi * 8;
  bf16x8 qf[4];
#pragma unroll
  for (int dc = 0; dc < 4; ++dc) qf[dc] = *(const bf16x8*)(qp + dc * 16);

  const u16* kst = k + (size_t)bh * 2048 * 64;
  const u16* vst = vt + (size_t)bh * 64 * 2048;

  f32x16 ot0 = {0, 0, 0, 0, 0, 0, 0, 0, 0, 0, 0, 0, 0, 0, 0, 0};
  f32x16 ot1 = ot0;
  float mrun = -1e30f, lsum = 0.0f;

  // stage tile tl (64 keys) into buffer b: 256 threads x 2 chunks x (K,V)
  auto STAGE = [&](int tl, int b) {
    int kb = tl << 6;
#pragma unroll
    for (int i = 0; i < 2; ++i) {
      int seg = i * 4 + wave;          // wave-uniform LDS segment
      int li = seg * 64 + lane;        // linear 16B-chunk index 0..511
      int row = li >> 3, ch = li & 7;
      int sw = (ch ^ (row & 7)) << 3;  // pre-swizzled source chunk (u16 units)
      gload_lds16(kst + (size_t)(kb + row) * 64 + sw, (void*)&KT[b][seg * 512]);
      gload_lds16(vst + (size_t)row * 2048 + kb + sw, (void*)&VT[b][seg * 512]);
    }
  };

  int cur = 0;
  STAGE(0, 0);
  __syncthreads();  // compiler drains vmcnt before barrier -> tile 0 ready

  for (int tl = 0; tl < 32; ++tl) {
    if (tl < 31) STAGE(tl + 1, cur ^ 1);
#pragma unroll
    for (int sub = 0; sub < 2; ++sub) {
      // K fragments from LDS (swizzled read)
      bf16x8 kf[4];
#pragma unroll
      for (int dc = 0; dc < 4; ++dc)
        kf[dc] = *(const bf16x8*)&KT[cur][((sub * 32 + ql) << 6) +
                                          ((((dc << 1) | hi) ^ (ql & 7)) << 3)];
      // V^T fragments from LDS
      bf16x8 vf[4];
#pragma unroll
      for (int kc = 0; kc < 2; ++kc)
#pragma unroll
        for (int dh = 0; dh < 2; ++dh)
          vf[kc * 2 + dh] =
              *(const bf16x8*)&VT[cur][(((dh << 5) + ql) << 6) +
                                       (((sub * 4 + (kc << 1) + hi) ^ (ql & 7)) << 3)];
      // S^T[k][q] = sum_d K[k][d] Q[q][d]
      f32x16 st = {0, 0, 0, 0, 0, 0, 0, 0, 0, 0, 0, 0, 0, 0, 0, 0};
      __builtin_amdgcn_s_setprio(1);
#pragma unroll
      for (int dc = 0; dc < 4; ++dc)
        st = __builtin_amdgcn_mfma_f32_32x32x16_bf16(kf[dc], qf[dc], st, 0, 0, 0);
      __builtin_amdgcn_s_setprio(0);
      // online softmax (q-row = lane&31; k-halves across hi). Tree reductions.
      float a8[8];
#pragma unroll
      for (int r = 0; r < 8; ++r) a8[r] = fmaxf(st[2 * r], st[2 * r + 1]);
#pragma unroll
      for (int r = 0; r < 4; ++r) a8[r] = fmaxf(a8[r], a8[r + 4]);
      float smax = fmaxf(fmaxf(a8[0], a8[2]), fmaxf(a8[1], a8[3]));
      smax = fmaxf(smax, __shfl_xor(smax, 32));
      float mnew = fmaxf(mrun, smax);
      if (!__all(smax <= mrun + 8.0f)) {  // defer-max: rescale rarely
        float sf = fexp2((mrun - mnew) * C_LOG2E);
#pragma unroll
        for (int r = 0; r < 16; ++r) { ot0[r] *= sf; ot1[r] *= sf; }
        lsum *= sf;
        mrun = mnew;
      }
      float aa = mrun * C_LOG2E;
      float p[16];
#pragma unroll
      for (int r = 0; r < 16; ++r) p[r] = fexp2(st[r] * C_LOG2E - aa);
      float s8[8];
#pragma unroll
      for (int r = 0; r < 8; ++r) s8[r] = p[2 * r] + p[2 * r + 1];
#pragma unroll
      for (int r = 0; r < 4; ++r) s8[r] = s8[r] + s8[r + 4];
      float ts = (s8[0] + s8[2]) + (s8[1] + s8[3]);
      ts += __shfl_xor(ts, 32);
      lsum += ts;
      // P -> bf16 B-fragments via permlane32_swap, O^T += V^T @ P^T
      __builtin_amdgcn_s_setprio(1);
#pragma unroll
      for (int kc = 0; kc < 2; ++kc) {
        u32 x0 = cvtpk(p[kc * 8 + 0], p[kc * 8 + 1]), x1 = cvtpk(p[kc * 8 + 2], p[kc * 8 + 3]);
        u32 y0 = cvtpk(p[kc * 8 + 4], p[kc * 8 + 5]), y1 = cvtpk(p[kc * 8 + 6], p[kc * 8 + 7]);
        // swap x.hi <-> y.lo: x' = {x.lo, y.lo}, y' = {x.hi, y.hi}
        asm("v_permlane32_swap_b32 %0, %1" : "+v"(x0), "+v"(y0));
        asm("v_permlane32_swap_b32 %0, %1" : "+v"(x1), "+v"(y1));
        union { u32 u[4]; bf16x8 v8; } pf;
        pf.u[0] = x0;
        pf.u[1] = x1;
        pf.u[2] = y0;
        pf.u[3] = y1;
        ot0 = __builtin_amdgcn_mfma_f32_32x32x16_bf16(vf[kc * 2 + 0], pf.v8, ot0, 0, 0, 0);
        ot1 = __builtin_amdgcn_mfma_f32_32x32x16_bf16(vf[kc * 2 + 1], pf.v8, ot1, 0, 0, 0);
      }
      __builtin_amdgcn_s_setprio(0);
    }
    __syncthreads();  // all waves done with buf[cur]; stage(t+1) drained
    cur ^= 1;
  }

  float inv = 1.0f / lsum;
  int b = bh >> 4, h = bh & 15;
  size_t ob = ((size_t)b * 2048 + q0 + ql) * 1024 + h * 64;
#pragma unroll
  for (int r = 0; r < 16; ++r) {
    int d = (r & 3) + ((r >> 2) << 3) + hi * 4;
    o[ob + d] = f2bf(ot0[r] * inv);
    o[ob + 32 + d] = f2bf(ot1[r] * inv);
  }
}

extern "C" void kernel_launch(void* const* d_in, const int* in_sizes, int n_in,
                              void* d_out, int out_size, void* d_ws, size_t ws_size,
                              hipStream_t stream) {
  const float* x = (const float*)d_in[0];
  // d_in[1] positions: provably irrelevant (mask all-true at N=2048)
  const float* w_qkv = (const float*)d_in[2];
  const float* b_qkv = (const float*)d_in[3];
  const float* w_out = (const float*)d_in[4];
  const float* b_out = (const float*)d_in[5];
  const float* w_ff1 = (const float*)d_in[6];
  const float* b_ff1 = (const float*)d_in[7];
  const float* w_ff2 = (const float*)d_in[8];
  const float* b_ff2 = (const float*)d_in[9];
  const float* g1 = (const float*)d_in[10];
  const float* be1 = (const float*)d_in[11];
  const float* g2 = (const float*)d_in[12];
  const float* be2 = (const float*)d_in[13];
  float* out = (float*)d_out;

  char* wp = (char*)d_ws;
  u16* wqkvT = (u16*)wp; wp += (size_t)3072 * 1024 * 2;
  u16* woutT = (u16*)wp; wp += (size_t)1024 * 1024 * 2;
  u16* wff1T = (u16*)wp; wp += (size_t)4096 * 1024 * 2;
  u16* wff2T = (u16*)wp; wp += (size_t)1024 * 4096 * 2;
  u16* xn    = (u16*)wp; wp += (size_t)4096 * 1024 * 2;   // reused for xn2
  float* x2  = (float*)wp; wp += (size_t)4096 * 1024 * 4;
  u16* qbuf  = (u16*)wp; wp += (size_t)32 * 2048 * 64 * 2;
  u16* kbuf  = (u16*)wp; wp += (size_t)32 * 2048 * 64 * 2;
  u16* vtbuf = (u16*)wp; wp += (size_t)32 * 2048 * 64 * 2;  // V^T (b,h,d,n)
  u16* attnb = (u16*)wp; wp += (size_t)4096 * 1024 * 2;
  u16* ffh   = qbuf;  // alias: ff hidden (33.5MB) reuses q/k/v region after attention

  // weights -> bf16, transposed to (N x K)
  k_transpose_bf16<<<dim3(3072 / 32, 1024 / 32), 256, 0, stream>>>(w_qkv, wqkvT, 1024, 3072);
  k_transpose_bf16<<<dim3(1024 / 32, 1024 / 32), 256, 0, stream>>>(w_out, woutT, 1024, 1024);
  k_transpose_bf16<<<dim3(4096 / 32, 1024 / 32), 256, 0, stream>>>(w_ff1, wff1T, 1024, 4096);
  k_transpose_bf16<<<dim3(1024 / 32, 4096 / 32), 256, 0, stream>>>(w_ff2, wff2T, 4096, 1024);

  k_layernorm<<<4096, 256, 0, stream>>>(x, g1, be1, xn);
  k_gemm<0, 1><<<dim3(24, 32), 256, 0, stream>>>(xn, wqkvT, 1024, 3072, b_qkv, nullptr,
                                                 qbuf, kbuf, vtbuf);
  k_attn<<<dim3(16, 32), 256, 0, stream>>>(qbuf, kbuf, vtbuf, attnb);
  k_gemm<1, 2><<<dim3(8, 32), 512, 0, stream>>>(attnb, woutT, 1024, 1024, b_out, x,
                                                x2, nullptr, nullptr);
  k_layernorm<<<4096, 256, 0, stream>>>(x2, g2, be2, xn);
  k_gemm<2, 1><<<dim3(32, 32), 256, 0, stream>>>(xn, wff1T, 1024, 4096, b_ff1, nullptr,
                                                 ffh, nullptr, nullptr);
  k_gemm<3, 2><<<dim3(8, 32), 512, 0, stream>>>(ffh, wff2T, 4096, 1024, b_ff2, x2,
                                                out, nullptr, nullptr);
}